// Round 8
// baseline (1445.814 us; speedup 1.0000x reference)
//
#include <hip/hip_runtime.h>

// ============================================================================
// Bidirectional LSTM encoder, MI355X.  R8: dual-direction interleaved wgs.
//   - 32 wgs; each wg owns R6's (dir,r) slice for BOTH dirs (64 cols each).
//   - per iter: check_f/stage -> [issue bwd polls] MFMA_f -> gates_f+publish ->
//     check_b/stage -> [issue next fwd polls] MFMA_b -> gates_b+publish.
//     Poll loads age ~1.5-2us before checking -> fresh on round ~1.
//   - raw s_barrier + lgkmcnt(0) only (no vmcnt drain; polls stay in flight).
//   - tag-in-data sync (dword = bf16<<16 | step), per-chunk verify/retry.
// ============================================================================

typedef unsigned short u16;
typedef unsigned int   u32;
typedef u16   u16x8 __attribute__((ext_vector_type(8)));
typedef u16   u16x4 __attribute__((ext_vector_type(4)));
typedef u32   u32x4 __attribute__((ext_vector_type(4)));
typedef __bf16 bf16x8 __attribute__((ext_vector_type(8)));
typedef float f32x4 __attribute__((ext_vector_type(4)));

#define EP 320            // padded E (300 -> 320)
#define NC 4096           // 2 dirs * 4H

static const size_t OFF_AEMB = 0;                              // 8192*320*2
static const size_t OFF_WPT  = OFF_AEMB + (size_t)8192*EP*2;
static const size_t OFF_BIAS = OFF_WPT  + (size_t)NC*EP*2;     // f32[4096]
static const size_t OFF_UPT  = OFF_BIAS + (size_t)NC*4;        // bf16 [4096][512]
static const size_t OFF_MASK = OFF_UPT  + (size_t)NC*512*2;    // u32 [32][8]
static const size_t OFF_HIMG = OFF_MASK + 1024;                // u32 2dir*2par*16384 dwords
static const size_t OFF_XW   = OFF_HIMG + (size_t)2*2*16384*4; // bf16 [8192][4096]

__device__ __forceinline__ u16 f2bf(float f){               // RNE
  u32 u = __builtin_bit_cast(u32, f);
  return (u16)((u + 0x7FFFu + ((u >> 16) & 1u)) >> 16);
}
__device__ __forceinline__ float bf2f(u16 h){
  u32 u = ((u32)h) << 16; return __builtin_bit_cast(float, u);
}
__device__ __forceinline__ float sigm(float x){ return 1.f/(1.f+__expf(-x)); }
__device__ __forceinline__ float tanh_(float x){ return 2.f/(1.f+__expf(-2.f*x)) - 1.f; }

#define RAWBAR() do{ \
  asm volatile("s_waitcnt lgkmcnt(0)" ::: "memory"); \
  __builtin_amdgcn_sched_barrier(0); \
  __builtin_amdgcn_s_barrier(); \
  __builtin_amdgcn_sched_barrier(0); \
}while(0)

// ---------------------------------------------------------------- fused prep
// blocks: [0,8192) aemb | [8192,8256) W-transpose | [8256,8384) U-transpose |
//         [8384,8641) mask + tagged h-image init
__global__ __launch_bounds__(320) void k_prep(const int* __restrict__ x,
                                              const float* __restrict__ emb,
                                              const float* __restrict__ Wf, const float* __restrict__ Wb,
                                              const float* __restrict__ bfv, const float* __restrict__ bbv,
                                              const float* __restrict__ Uf, const float* __restrict__ Ub,
                                              const float* __restrict__ h0f, const float* __restrict__ h0b,
                                              u16* __restrict__ aemb, u16* __restrict__ wpt,
                                              float* __restrict__ bias, u16* __restrict__ upt,
                                              u32* __restrict__ maskb, u32* __restrict__ himg){
  __shared__ u16 lbuf[320*64];                 // 40 KB, reused by wt/ut parts
  int bid = blockIdx.x, tid = threadIdx.x;

  if (bid < 8192){                             // ---- aemb gather
    int m = bid, k = tid;
    int b = m & 31, t = m >> 5;
    int tok = x[b*256 + t];
    float v = (k < 300) ? emb[(size_t)tok*300 + k] : 0.f;
    aemb[(size_t)m*EP + k] = f2bf(v);
    return;
  }
  if (bid < 8256){                             // ---- W -> [col'][K] + bias
    int b2 = bid - 8192;                       // 0..63
    u16 (*lds)[64] = (u16(*)[64])lbuf;
    int c0 = b2*64; int dir = c0 >> 11;
    const float* W = dir ? Wb : Wf;
    if (tid < 256){
      int cl = tid & 63, rr = tid >> 6;
      int ci = (c0 + cl) & 2047; int srccol = (ci & 3)*512 + (ci >> 2);
      for (int kk = 0; kk < 80; kk++){
        int row = kk*4 + rr;
        float v = (row < 300) ? W[(size_t)row*2048 + srccol] : 0.f;
        lds[row][cl] = f2bf(v);
      }
    }
    __syncthreads();
    if (tid < 256){
      int cw = tid >> 2, kc = tid & 3;
      #pragma unroll
      for (int j = 0; j < 10; j++){
        u16x8 v;
        #pragma unroll
        for (int e = 0; e < 8; e++) v[e] = lds[kc*80 + j*8 + e][cw];
        *(u16x8*)&wpt[(size_t)(c0+cw)*EP + kc*80 + j*8] = v;
      }
      if (tid < 64){
        int ci2 = (c0 + tid) & 2047; int sc = (ci2 & 3)*512 + (ci2 >> 2);
        bias[c0 + tid] = (dir ? bbv : bfv)[sc];
      }
    }
    return;
  }
  if (bid < 8384){                             // ---- U -> [col'][K]
    int b2 = bid - 8256;                       // 0..127
    u16 (*lds)[32] = (u16(*)[32])lbuf;
    int cg0 = b2*32; int dir = cg0 >> 11;
    const float* U = dir ? Ub : Uf;
    if (tid < 256){
      int cl = tid & 31, rr = tid >> 5;
      int ci = (cg0 + cl) & 2047; int srccol = (ci & 3)*512 + (ci >> 2);
      for (int kk = 0; kk < 64; kk++){
        int row = kk*8 + rr;
        lds[row][cl] = f2bf(U[(size_t)row*2048 + srccol]);
      }
    }
    __syncthreads();
    if (tid < 256){
      int cw = tid >> 3, kc = tid & 7;
      #pragma unroll
      for (int j = 0; j < 8; j++){
        u16x8 v;
        #pragma unroll
        for (int e = 0; e < 8; e++) v[e] = lds[kc*64 + j*8 + e][cw];
        *(u16x8*)&upt[(size_t)(cg0+cw)*512 + kc*64 + j*8] = v;
      }
    }
    return;
  }
  {                                            // ---- mask + tagged image init
    int b2 = bid - 8384;                       // 0..256
    if (tid >= 256) return;
    if (b2 == 256){
      int b = tid >> 3, w = tid & 7;
      u32 m = 0;
      for (int i = 0; i < 32; i++){ int t = w*32 + i; m |= (u32)(x[b*256 + t] != 0) << i; }
      maskb[b*8 + w] = m;
      return;
    }
    int idx = b2*256 + tid;                    // 0 .. 65535
    int dir = idx >> 15, rem = idx & 32767, par = rem >> 14, di = rem & 16383;
    u32* img = himg + (size_t)dir*32768 + (size_t)par*16384;
    if (par == 0){
      img[di] = 0x0000DEADu;                   // invalid tag
    } else {
      int j = di & 7, lane2 = (di >> 3) & 63, ks = (di >> 9) & 15, mt = di >> 13;
      int b = mt*16 + (lane2 & 15), ug = ks*32 + (lane2 >> 4)*8 + j;
      const float* h0 = dir ? h0b : h0f;
      img[di] = ((u32)f2bf(h0[b*512 + ug]) << 16) | 0xFFFFu;   // h_{-1}, tag -1
    }
  }
}

// ---------------------------------------------------------------- input GEMM: xW+b (bf16 MFMA)
__global__ __launch_bounds__(512) void k_ingemm(const u16* __restrict__ aemb, const u16* __restrict__ wpt,
                                                const float* __restrict__ bias, u16* __restrict__ xw){
  int bx = blockIdx.x, by = blockIdx.y;        // 64 x 16
  int tid = threadIdx.x, lane = tid & 63, wv = tid >> 6;
  int m0 = bx*128 + wv*16;
  u16x8 afr[10];
  const u16* ap = aemb + (size_t)(m0 + (lane & 15))*EP + ((lane >> 4)*8);
  #pragma unroll
  for (int ks = 0; ks < 10; ks++) afr[ks] = *(const u16x8*)(ap + ks*32);
  #pragma unroll
  for (int n = 0; n < 16; n++){
    int colp = by*256 + n*16 + (lane & 15);
    const u16* bp = wpt + (size_t)colp*EP + ((lane >> 4)*8);
    f32x4 acc = {0.f, 0.f, 0.f, 0.f};
    #pragma unroll
    for (int ks = 0; ks < 10; ks++){
      bf16x8 bfr = __builtin_bit_cast(bf16x8, *(const u16x8*)(bp + ks*32));
      acc = __builtin_amdgcn_mfma_f32_16x16x32_bf16(__builtin_bit_cast(bf16x8, afr[ks]), bfr, acc, 0, 0, 0);
    }
    float bv = bias[colp];
    #pragma unroll
    for (int v = 0; v < 4; v++){
      int m = m0 + (lane >> 4)*4 + v;          // C/D: col=lane&15, row=(lane>>4)*4+reg  [m89]
      xw[(size_t)m*NC + colp] = f2bf(acc[v] + bv);
    }
  }
}

// ---------------------------------------------------------------- persistent recurrence
__global__ __launch_bounds__(512, 2) void k_recur(const u16* __restrict__ xw, const u16* __restrict__ upt,
                                                  const u32* __restrict__ maskb, u32* __restrict__ himg,
                                                  const float* __restrict__ c0f, const float* __restrict__ c0b,
                                                  const float* __restrict__ h0f, const float* __restrict__ h0b,
                                                  float* __restrict__ out){
  int r = blockIdx.x;                          // 0..31, rank in BOTH dir groups
  int tid = threadIdx.x, lane = tid & 63, wv = tid >> 6;
  int nw = wv & 3, kh = wv >> 2;               // wave's N-tile (of 4) and K-half

  __shared__ u16   astage[2][16384];           // per-dir bf16 frag image (64 KB)
  __shared__ float zbuf[2][32][64];            // [khalf][b][local col], 16 KB
  __shared__ u32   mk[32][8];

  // U-slices for both dirs as persistent B-fragments (col = r*64 + nw*16 + lane&15)
  bf16x8 bfr_f[8], bfr_b[8];
  {
    const u16* ubf = upt + ((size_t)0*2048 + r*64 + nw*16 + (lane & 15))*512 + ((lane >> 4)*8);
    const u16* ubb = upt + ((size_t)1*2048 + r*64 + nw*16 + (lane & 15))*512 + ((lane >> 4)*8);
    #pragma unroll
    for (int i = 0; i < 8; i++){
      int ks = kh*8 + i;
      bfr_f[i] = __builtin_bit_cast(bf16x8, *(const u16x8*)(ubf + ks*32));
      bfr_b[i] = __builtin_bit_cast(bf16x8, *(const u16x8*)(ubb + ks*32));
    }
  }
  int b = tid >> 4, u = tid & 15, ug = r*16 + u;
  float cf = c0f[b*512 + ug], hf = h0f[b*512 + ug];
  float cb = c0b[b*512 + ug], hb = h0b[b*512 + ug];
  if (tid < 256) mk[tid >> 3][tid & 7] = maskb[tid];
  __syncthreads();

  u32* imgf = himg;
  u32* imgb = himg + 32768;
  int ks2 = r >> 1, qv = ((r & 1) << 1) | (u >> 3);
  size_t dpub = (((size_t)(b >> 4)*16 + ks2)*64 + (size_t)(qv*16 + (b & 15)))*8 + (u & 7);

  u16x4 pref_f = *(const u16x4*)(xw + (size_t)(0*32 + b)*NC + r*64 + u*4);
  u16x4 pref_b = *(const u16x4*)(xw + (size_t)(255*32 + b)*NC + 2048 + r*64 + u*4);

  u32x4 vf0, vf1, vf2, vf3, vf4, vf5, vf6, vf7;   // fwd poll chunks in flight
  u32x4 vb0, vb1, vb2, vb3, vb4, vb5, vb6, vb7;   // bwd poll chunks in flight

  #define LDF(i, base) asm volatile("global_load_dwordx4 %0, %1, off sc0 sc1" : "=v"(vf##i) : "v"((base) + i*8192))
  #define LDB(i, base) asm volatile("global_load_dwordx4 %0, %1, off sc0 sc1" : "=v"(vb##i) : "v"((base) + i*8192))

  // prologue: issue fwd polls for s=0 (parity 1)
  const char* gpf = (const char*)(imgf + 16384) + (size_t)tid*16;
  LDF(0,gpf); LDF(1,gpf); LDF(2,gpf); LDF(3,gpf); LDF(4,gpf); LDF(5,gpf); LDF(6,gpf); LDF(7,gpf);

  for (int s = 0; s < 256; ++s){
    int pr = (s + 1) & 1;
    u32 tg = (u32)((s - 1) & 0xFFFF);
    const char* gpb = (const char*)(imgb + (size_t)pr*16384) + (size_t)tid*16;

    // ======== check fwd: verify tags, stage astage[0], retry stale chunks
    {
      u32 pend = 255u;
      for (;;){
        asm volatile("s_waitcnt vmcnt(0)" ::: "memory");
        __builtin_amdgcn_sched_barrier(0);
        #define CKF(i) if (pend & (1u << i)){ \
          if ((((vf##i.x ^ tg) | (vf##i.y ^ tg) | (vf##i.z ^ tg) | (vf##i.w ^ tg)) & 0xFFFFu) == 0u){ \
            u16x4 p; p[0] = (u16)(vf##i.x >> 16); p[1] = (u16)(vf##i.y >> 16); \
                     p[2] = (u16)(vf##i.z >> 16); p[3] = (u16)(vf##i.w >> 16); \
            *(u16x4*)((char*)&astage[0][0] + (size_t)tid*8 + i*4096) = p; \
            pend &= ~(1u << i); \
          } else { LDF(i, gpf); } }
        CKF(0); CKF(1); CKF(2); CKF(3); CKF(4); CKF(5); CKF(6); CKF(7);
        #undef CKF
        if (!pend) break;
      }
    }
    if (s > 0) out[(size_t)(b*256 + (s-1))*1024 + ug] = hf;      // deferred fwd h_{s-1}
    RAWBAR();                                   // B_f: astage[0] ready

    // ======== issue bwd polls now (age during MFMA_f + gates_f)
    LDB(0,gpb); LDB(1,gpb); LDB(2,gpb); LDB(3,gpb); LDB(4,gpb); LDB(5,gpb); LDB(6,gpb); LDB(7,gpb);
    int sn = (s < 255) ? s + 1 : s;
    u16x4 nxt_f = *(const u16x4*)(xw + (size_t)(sn*32 + b)*NC + r*64 + u*4);
    u16x4 nxt_b = *(const u16x4*)(xw + (size_t)((255-sn)*32 + b)*NC + 2048 + r*64 + u*4);

    // ======== MFMA fwd
    {
      f32x4 acc0 = {0.f,0.f,0.f,0.f}, acc1 = {0.f,0.f,0.f,0.f};
      const u16* ab = &astage[0][0] + lane*8;
      #pragma unroll
      for (int i = 0; i < 8; i++){
        int ks = kh*8 + i;
        bf16x8 a0 = __builtin_bit_cast(bf16x8, *(const u16x8*)(ab + (size_t)ks*512));
        bf16x8 a1 = __builtin_bit_cast(bf16x8, *(const u16x8*)(ab + (size_t)(16 + ks)*512));
        acc0 = __builtin_amdgcn_mfma_f32_16x16x32_bf16(a0, bfr_f[i], acc0, 0, 0, 0);
        acc1 = __builtin_amdgcn_mfma_f32_16x16x32_bf16(a1, bfr_f[i], acc1, 0, 0, 0);
      }
      int row0 = (lane >> 4)*4, cc = nw*16 + (lane & 15);
      #pragma unroll
      for (int v = 0; v < 4; v++){
        zbuf[kh][row0 + v][cc]      = acc0[v];
        zbuf[kh][16 + row0 + v][cc] = acc1[v];
      }
    }
    RAWBAR();                                   // C_f: zbuf ready

    // ======== gates fwd (t = s), publish fwd
    {
      f32x4 za = *(const f32x4*)&zbuf[0][b][u*4];
      f32x4 zc = *(const f32x4*)&zbuf[1][b][u*4];
      float zi = za[0] + zc[0] + bf2f(pref_f[0]);
      float zf = za[1] + zc[1] + bf2f(pref_f[1]);
      float zg = za[2] + zc[2] + bf2f(pref_f[2]);
      float zo = za[3] + zc[3] + bf2f(pref_f[3]);
      float gi = sigm(zi), gf = sigm(zf), gg = tanh_(zg), go = sigm(zo);
      float cn = gf*cf + gi*gg;
      float hn = go*tanh_(cn);
      if ((mk[b][s >> 5] >> (s & 31)) & 1){ cf = cn; hf = hn; }
      if (s < 255){
        u32 dw = ((u32)f2bf(hf) << 16) | (u32)s;
        u32* gdst = imgf + (size_t)(s & 1)*16384 + dpub;
        asm volatile("global_store_dword %0, %1, off sc0 sc1" :: "v"(gdst), "v"(dw) : "memory");
      }
      pref_f = nxt_f;
    }

    // ======== check bwd: verify tags, stage astage[1], retry stale chunks
    {
      u32 pend = 255u;
      for (;;){
        asm volatile("s_waitcnt vmcnt(0)" ::: "memory");
        __builtin_amdgcn_sched_barrier(0);
        #define CKB(i) if (pend & (1u << i)){ \
          if ((((vb##i.x ^ tg) | (vb##i.y ^ tg) | (vb##i.z ^ tg) | (vb##i.w ^ tg)) & 0xFFFFu) == 0u){ \
            u16x4 p; p[0] = (u16)(vb##i.x >> 16); p[1] = (u16)(vb##i.y >> 16); \
                     p[2] = (u16)(vb##i.z >> 16); p[3] = (u16)(vb##i.w >> 16); \
            *(u16x4*)((char*)&astage[1][0] + (size_t)tid*8 + i*4096) = p; \
            pend &= ~(1u << i); \
          } else { LDB(i, gpb); } }
        CKB(0); CKB(1); CKB(2); CKB(3); CKB(4); CKB(5); CKB(6); CKB(7);
        #undef CKB
        if (!pend) break;
      }
    }
    if (s > 0) out[(size_t)(b*256 + (256-s))*1024 + 512 + ug] = hb;   // deferred bwd h_{s-1}
    RAWBAR();                                   // B_b: astage[1] ready

    // ======== issue NEXT fwd polls (parity (s+2)&1 = s&1); age during MFMA_b+gates_b
    if (s < 255){
      gpf = (const char*)(imgf + (size_t)(s & 1)*16384) + (size_t)tid*16;
      LDF(0,gpf); LDF(1,gpf); LDF(2,gpf); LDF(3,gpf); LDF(4,gpf); LDF(5,gpf); LDF(6,gpf); LDF(7,gpf);
    }

    // ======== MFMA bwd
    {
      f32x4 acc0 = {0.f,0.f,0.f,0.f}, acc1 = {0.f,0.f,0.f,0.f};
      const u16* ab = &astage[1][0] + lane*8;
      #pragma unroll
      for (int i = 0; i < 8; i++){
        int ks = kh*8 + i;
        bf16x8 a0 = __builtin_bit_cast(bf16x8, *(const u16x8*)(ab + (size_t)ks*512));
        bf16x8 a1 = __builtin_bit_cast(bf16x8, *(const u16x8*)(ab + (size_t)(16 + ks)*512));
        acc0 = __builtin_amdgcn_mfma_f32_16x16x32_bf16(a0, bfr_b[i], acc0, 0, 0, 0);
        acc1 = __builtin_amdgcn_mfma_f32_16x16x32_bf16(a1, bfr_b[i], acc1, 0, 0, 0);
      }
      int row0 = (lane >> 4)*4, cc = nw*16 + (lane & 15);
      #pragma unroll
      for (int v = 0; v < 4; v++){
        zbuf[kh][row0 + v][cc]      = acc0[v];
        zbuf[kh][16 + row0 + v][cc] = acc1[v];
      }
    }
    RAWBAR();                                   // C_b: zbuf ready

    // ======== gates bwd (t = 255 - s), publish bwd
    {
      int t = 255 - s;
      f32x4 za = *(const f32x4*)&zbuf[0][b][u*4];
      f32x4 zc = *(const f32x4*)&zbuf[1][b][u*4];
      float zi = za[0] + zc[0] + bf2f(pref_b[0]);
      float zf = za[1] + zc[1] + bf2f(pref_b[1]);
      float zg = za[2] + zc[2] + bf2f(pref_b[2]);
      float zo = za[3] + zc[3] + bf2f(pref_b[3]);
      float gi = sigm(zi), gf = sigm(zf), gg = tanh_(zg), go = sigm(zo);
      float cn = gf*cb + gi*gg;
      float hn = go*tanh_(cn);
      if ((mk[b][t >> 5] >> (t & 31)) & 1){ cb = cn; hb = hn; }
      if (s < 255){
        u32 dw = ((u32)f2bf(hb) << 16) | (u32)s;
        u32* gdst = imgb + (size_t)(s & 1)*16384 + dpub;
        asm volatile("global_store_dword %0, %1, off sc0 sc1" :: "v"(gdst), "v"(dw) : "memory");
      }
      pref_b = nxt_b;
    }
    RAWBAR();                                   // end-of-iter: astage[0] reusable
  }
  #undef LDF
  #undef LDB

  // ---- finals
  out[(size_t)(b*256 + 255)*1024 + ug] = hf;
  out[(size_t)(b*256 + 0)*1024 + 512 + ug] = hb;
  out[8388608 + b*512 + ug] = hf;                    // h_f
  out[8388608 + 16384 + b*512 + ug] = hb;            // h_b
  out[8388608 + 32768 + b*512 + ug] = cf;            // c_f
  out[8388608 + 32768 + 16384 + b*512 + ug] = cb;    // c_b
}

// ----------------------------------------------------------------------------
extern "C" void kernel_launch(void* const* d_in, const int* in_sizes, int n_in,
                              void* d_out, int out_size, void* d_ws, size_t ws_size,
                              hipStream_t stream){
  const int*   x   = (const int*)  d_in[0];
  const float* h0f = (const float*)d_in[1];
  const float* c0f = (const float*)d_in[2];
  const float* h0b = (const float*)d_in[3];
  const float* c0b = (const float*)d_in[4];
  const float* emb = (const float*)d_in[5];
  const float* Wf  = (const float*)d_in[6];
  const float* Uf  = (const float*)d_in[7];
  const float* bfv = (const float*)d_in[8];
  const float* Wb  = (const float*)d_in[9];
  const float* Ub  = (const float*)d_in[10];
  const float* bbv = (const float*)d_in[11];
  float* out = (float*)d_out;

  char* w = (char*)d_ws;
  u16*   aemb = (u16*)(w + OFF_AEMB);
  u16*   wpt  = (u16*)(w + OFF_WPT);
  float* bias = (float*)(w + OFF_BIAS);
  u16*   upt  = (u16*)(w + OFF_UPT);
  u32*   mskb = (u32*)(w + OFF_MASK);
  u32*   himg = (u32*)(w + OFF_HIMG);
  u16*   xw   = (u16*)(w + OFF_XW);

  k_prep  <<<dim3(8641),  dim3(320), 0, stream>>>(x, emb, Wf, Wb, bfv, bbv, Uf, Ub,
                                                  h0f, h0b, aemb, wpt, bias, upt, mskb, himg);
  k_ingemm<<<dim3(64,16), dim3(512), 0, stream>>>(aemb, wpt, bias, xw);
  k_recur <<<dim3(32),    dim3(512), 0, stream>>>(xw, upt, mskb, himg,
                                                  c0f, c0b, h0f, h0b, out);
}

// Round 9
// 962.952 us; speedup vs baseline: 1.5014x; 1.5014x over previous
//
#include <hip/hip_runtime.h>

// ============================================================================
// Bidirectional LSTM encoder, MI355X.  R9: R6 sync + full-K waves, 1 barrier.
//   - 2 groups (fwd/bwd) x 32 wgs, 8 waves each. Wave = (m-tile, N-tile):
//     16 MFMA full K -> in-wave quad 4x4 transpose (R4-validated) -> gates ->
//     immediate tagged publish. No zbuf, ONE barrier per step.
//   - astage double-buffered (parity); raw s_barrier + lgkmcnt(0) only.
//   - tag-in-data sync (dword = bf16<<16 | step), 8-chunk verify/retry reader.
//   - fused prep + 256-col ingemm (R7 front-end).
// ============================================================================

typedef unsigned short u16;
typedef unsigned int   u32;
typedef u16   u16x8 __attribute__((ext_vector_type(8)));
typedef u16   u16x4 __attribute__((ext_vector_type(4)));
typedef u32   u32x4 __attribute__((ext_vector_type(4)));
typedef __bf16 bf16x8 __attribute__((ext_vector_type(8)));
typedef float f32x4 __attribute__((ext_vector_type(4)));

#define EP 320            // padded E (300 -> 320)
#define NC 4096           // 2 dirs * 4H

static const size_t OFF_AEMB = 0;                              // 8192*320*2
static const size_t OFF_WPT  = OFF_AEMB + (size_t)8192*EP*2;
static const size_t OFF_BIAS = OFF_WPT  + (size_t)NC*EP*2;     // f32[4096]
static const size_t OFF_UPT  = OFF_BIAS + (size_t)NC*4;        // bf16 [4096][512]
static const size_t OFF_MASK = OFF_UPT  + (size_t)NC*512*2;    // u32 [32][8]
static const size_t OFF_HIMG = OFF_MASK + 1024;                // u32 2dir*2par*16384 dwords
static const size_t OFF_XW   = OFF_HIMG + (size_t)2*2*16384*4; // bf16 [8192][4096]

__device__ __forceinline__ u16 f2bf(float f){               // RNE
  u32 u = __builtin_bit_cast(u32, f);
  return (u16)((u + 0x7FFFu + ((u >> 16) & 1u)) >> 16);
}
__device__ __forceinline__ float bf2f(u16 h){
  u32 u = ((u32)h) << 16; return __builtin_bit_cast(float, u);
}
__device__ __forceinline__ float sigm(float x){ return 1.f/(1.f+__expf(-x)); }
__device__ __forceinline__ float tanh_(float x){ return 2.f/(1.f+__expf(-2.f*x)) - 1.f; }

#define RAWBAR() do{ \
  asm volatile("s_waitcnt lgkmcnt(0)" ::: "memory"); \
  __builtin_amdgcn_sched_barrier(0); \
  __builtin_amdgcn_s_barrier(); \
  __builtin_amdgcn_sched_barrier(0); \
}while(0)

// ---------------------------------------------------------------- fused prep
__global__ __launch_bounds__(320) void k_prep(const int* __restrict__ x,
                                              const float* __restrict__ emb,
                                              const float* __restrict__ Wf, const float* __restrict__ Wb,
                                              const float* __restrict__ bfv, const float* __restrict__ bbv,
                                              const float* __restrict__ Uf, const float* __restrict__ Ub,
                                              const float* __restrict__ h0f, const float* __restrict__ h0b,
                                              u16* __restrict__ aemb, u16* __restrict__ wpt,
                                              float* __restrict__ bias, u16* __restrict__ upt,
                                              u32* __restrict__ maskb, u32* __restrict__ himg){
  __shared__ u16 lbuf[320*64];                 // 40 KB, reused by wt/ut parts
  int bid = blockIdx.x, tid = threadIdx.x;

  if (bid < 8192){                             // ---- aemb gather
    int m = bid, k = tid;
    int b = m & 31, t = m >> 5;
    int tok = x[b*256 + t];
    float v = (k < 300) ? emb[(size_t)tok*300 + k] : 0.f;
    aemb[(size_t)m*EP + k] = f2bf(v);
    return;
  }
  if (bid < 8256){                             // ---- W -> [col'][K] + bias
    int b2 = bid - 8192;                       // 0..63
    u16 (*lds)[64] = (u16(*)[64])lbuf;
    int c0 = b2*64; int dir = c0 >> 11;
    const float* W = dir ? Wb : Wf;
    if (tid < 256){
      int cl = tid & 63, rr = tid >> 6;
      int ci = (c0 + cl) & 2047; int srccol = (ci & 3)*512 + (ci >> 2);
      for (int kk = 0; kk < 80; kk++){
        int row = kk*4 + rr;
        float v = (row < 300) ? W[(size_t)row*2048 + srccol] : 0.f;
        lds[row][cl] = f2bf(v);
      }
    }
    __syncthreads();
    if (tid < 256){
      int cw = tid >> 2, kc = tid & 3;
      #pragma unroll
      for (int j = 0; j < 10; j++){
        u16x8 v;
        #pragma unroll
        for (int e = 0; e < 8; e++) v[e] = lds[kc*80 + j*8 + e][cw];
        *(u16x8*)&wpt[(size_t)(c0+cw)*EP + kc*80 + j*8] = v;
      }
      if (tid < 64){
        int ci2 = (c0 + tid) & 2047; int sc = (ci2 & 3)*512 + (ci2 >> 2);
        bias[c0 + tid] = (dir ? bbv : bfv)[sc];
      }
    }
    return;
  }
  if (bid < 8384){                             // ---- U -> [col'][K]
    int b2 = bid - 8256;                       // 0..127
    u16 (*lds)[32] = (u16(*)[32])lbuf;
    int cg0 = b2*32; int dir = cg0 >> 11;
    const float* U = dir ? Ub : Uf;
    if (tid < 256){
      int cl = tid & 31, rr = tid >> 5;
      int ci = (cg0 + cl) & 2047; int srccol = (ci & 3)*512 + (ci >> 2);
      for (int kk = 0; kk < 64; kk++){
        int row = kk*8 + rr;
        lds[row][cl] = f2bf(U[(size_t)row*2048 + srccol]);
      }
    }
    __syncthreads();
    if (tid < 256){
      int cw = tid >> 3, kc = tid & 7;
      #pragma unroll
      for (int j = 0; j < 8; j++){
        u16x8 v;
        #pragma unroll
        for (int e = 0; e < 8; e++) v[e] = lds[kc*64 + j*8 + e][cw];
        *(u16x8*)&upt[(size_t)(cg0+cw)*512 + kc*64 + j*8] = v;
      }
    }
    return;
  }
  {                                            // ---- mask + tagged image init
    int b2 = bid - 8384;                       // 0..256
    if (tid >= 256) return;
    if (b2 == 256){
      int b = tid >> 3, w = tid & 7;
      u32 m = 0;
      for (int i = 0; i < 32; i++){ int t = w*32 + i; m |= (u32)(x[b*256 + t] != 0) << i; }
      maskb[b*8 + w] = m;
      return;
    }
    int idx = b2*256 + tid;                    // 0 .. 65535
    int dir = idx >> 15, rem = idx & 32767, par = rem >> 14, di = rem & 16383;
    u32* img = himg + (size_t)dir*32768 + (size_t)par*16384;
    if (par == 0){
      img[di] = 0x0000DEADu;                   // invalid tag
    } else {
      int j = di & 7, lane2 = (di >> 3) & 63, ks = (di >> 9) & 15, mt = di >> 13;
      int b = mt*16 + (lane2 & 15), ug = ks*32 + (lane2 >> 4)*8 + j;
      const float* h0 = dir ? h0b : h0f;
      img[di] = ((u32)f2bf(h0[b*512 + ug]) << 16) | 0xFFFFu;   // h_{-1}, tag -1
    }
  }
}

// ---------------------------------------------------------------- input GEMM: xW+b (bf16 MFMA)
__global__ __launch_bounds__(512) void k_ingemm(const u16* __restrict__ aemb, const u16* __restrict__ wpt,
                                                const float* __restrict__ bias, u16* __restrict__ xw){
  int bx = blockIdx.x, by = blockIdx.y;        // 64 x 16
  int tid = threadIdx.x, lane = tid & 63, wv = tid >> 6;
  int m0 = bx*128 + wv*16;
  u16x8 afr[10];
  const u16* ap = aemb + (size_t)(m0 + (lane & 15))*EP + ((lane >> 4)*8);
  #pragma unroll
  for (int ks = 0; ks < 10; ks++) afr[ks] = *(const u16x8*)(ap + ks*32);
  #pragma unroll
  for (int n = 0; n < 16; n++){
    int colp = by*256 + n*16 + (lane & 15);
    const u16* bp = wpt + (size_t)colp*EP + ((lane >> 4)*8);
    f32x4 acc = {0.f, 0.f, 0.f, 0.f};
    #pragma unroll
    for (int ks = 0; ks < 10; ks++){
      bf16x8 bfr = __builtin_bit_cast(bf16x8, *(const u16x8*)(bp + ks*32));
      acc = __builtin_amdgcn_mfma_f32_16x16x32_bf16(__builtin_bit_cast(bf16x8, afr[ks]), bfr, acc, 0, 0, 0);
    }
    float bv = bias[colp];
    #pragma unroll
    for (int v = 0; v < 4; v++){
      int m = m0 + (lane >> 4)*4 + v;          // C/D: col=lane&15, row=(lane>>4)*4+reg  [m89]
      xw[(size_t)m*NC + colp] = f2bf(acc[v] + bv);
    }
  }
}

// ---------------------------------------------------------------- persistent recurrence
__global__ __launch_bounds__(512, 2) void k_recur(const u16* __restrict__ xw, const u16* __restrict__ upt,
                                                  const u32* __restrict__ maskb, u32* __restrict__ himg,
                                                  const float* __restrict__ c0f, const float* __restrict__ c0b,
                                                  const float* __restrict__ h0f, const float* __restrict__ h0b,
                                                  float* __restrict__ out){
  int bid = blockIdx.x;                        // 64 wgs
  int dir = bid & 1, r = bid >> 1;             // direction, rank in group (0..31)
  int tid = threadIdx.x, lane = tid & 63, wv = tid >> 6;
  int nt = wv & 3, mt = wv >> 2;               // wave's N-tile (16 cols) and m-tile (16 rows)

  __shared__ u16 astage[2][16384];             // double-buffered bf16 frag image (64 KB)
  __shared__ u32 mk[32][8];

  // U-slice as persistent B-fragments, FULL K: cols r*64 + nt*16 + (lane&15)
  bf16x8 bfr[16];
  {
    const u16* ub = upt + ((size_t)dir*2048 + r*64 + nt*16 + (lane & 15))*512 + ((lane >> 4)*8);
    #pragma unroll
    for (int ks = 0; ks < 16; ks++)
      bfr[ks] = __builtin_bit_cast(bf16x8, *(const u16x8*)(ub + ks*32));
  }

  // lane's post-transpose gate identity (R4-validated mapping)
  int bq = (lane >> 4)*4 + (lane & 3);
  int u2 = (lane & 15) >> 2;
  int b  = mt*16 + bq;
  int ug = r*16 + nt*4 + u2;
  float c_reg = (dir ? c0b : c0f)[b*512 + ug];
  float h_reg = (dir ? h0b : h0f)[b*512 + ug];
  if (tid < 256) mk[tid >> 3][tid & 7] = maskb[tid];
  __syncthreads();

  u32* img = himg + (size_t)dir*32768;
  int ksp = ug >> 5, q = (ug >> 3) & 3, jj = ug & 7;
  size_t dpub = (((size_t)mt*16 + ksp)*64 + (size_t)(q*16 + (b & 15)))*8 + jj;

  int colb = r*64 + nt*16 + u2*4;              // xw column base for this lane's unit
  int t0 = dir ? 255 : 0;
  u16x4 pref = *(const u16x4*)(xw + (size_t)(t0*32 + b)*NC + dir*2048 + colb);

  bool sel0 = (lane & 1), sel1 = (lane & 2);

  for (int s = 0; s < 256; ++s){
    int t = dir ? 255 - s : s;
    u32 tg = (u32)((s - 1) & 0xFFFF);
    int pr = (s + 1) & 1;

    // ---- issue 8 tagged chunk loads (full 64KB image)
    const char* gsrc = (const char*)(img + (size_t)pr*16384) + (size_t)tid*16;
    u32x4 v0, v1, v2, v3, v4, v5, v6, v7;
    #define LD(i) asm volatile("global_load_dwordx4 %0, %1, off sc0 sc1" : "=v"(v##i) : "v"(gsrc + i*8192))
    LD(0); LD(1); LD(2); LD(3); LD(4); LD(5); LD(6); LD(7);

    // ---- aging fillers: next-step xw prefetch + deferred out-store of h_{s-1}
    int sn = (s < 255) ? s + 1 : s;
    int tn = dir ? 255 - sn : sn;
    u16x4 nxt = *(const u16x4*)(xw + (size_t)(tn*32 + b)*NC + dir*2048 + colb);
    if (s > 0){
      int tp = dir ? t + 1 : s - 1;
      out[(size_t)(b*256 + tp)*1024 + dir*512 + ug] = h_reg;
    }

    // ---- verify tags == s-1, stage verified chunks into astage[pr], retry stale
    {
      u32 pend = 255u;
      for (;;){
        asm volatile("s_waitcnt vmcnt(0)" ::: "memory");
        __builtin_amdgcn_sched_barrier(0);
        #define CK(i) if (pend & (1u << i)){ \
          if ((((v##i.x ^ tg) | (v##i.y ^ tg) | (v##i.z ^ tg) | (v##i.w ^ tg)) & 0xFFFFu) == 0u){ \
            u16x4 p; p[0] = (u16)(v##i.x >> 16); p[1] = (u16)(v##i.y >> 16); \
                     p[2] = (u16)(v##i.z >> 16); p[3] = (u16)(v##i.w >> 16); \
            *(u16x4*)((char*)&astage[pr][0] + (size_t)tid*8 + i*4096) = p; \
            pend &= ~(1u << i); \
          } else { LD(i); } }
        CK(0); CK(1); CK(2); CK(3); CK(4); CK(5); CK(6); CK(7);
        #undef CK
        if (!pend) break;
      }
    }
    #undef LD
    RAWBAR();                                   // astage[pr] ready (single barrier/step)

    // ---- z = h_{s-1} @ U : 16 MFMA, full K, one acc
    f32x4 acc = {0.f, 0.f, 0.f, 0.f};
    {
      const u16* ab = &astage[pr][0] + (size_t)(mt*16)*512 + lane*8;
      #pragma unroll
      for (int ks = 0; ks < 16; ks++){
        bf16x8 a = __builtin_bit_cast(bf16x8, *(const u16x8*)(ab + (size_t)ks*512));
        acc = __builtin_amdgcn_mfma_f32_16x16x32_bf16(a, bfr[ks], acc, 0, 0, 0);
      }
    }

    // ---- in-wave quad 4x4 transpose (R4-validated)
    f32x4 tt, rr, t2, o;
    #pragma unroll
    for (int e = 0; e < 4; e++) tt[e] = __shfl_xor(acc[e], 1);
    rr[0] = sel0 ? tt[1] : acc[0];  rr[1] = sel0 ? acc[1] : tt[0];
    rr[2] = sel0 ? tt[3] : acc[2];  rr[3] = sel0 ? acc[3] : tt[2];
    #pragma unroll
    for (int e = 0; e < 4; e++) t2[e] = __shfl_xor(rr[e], 2);
    o[0] = sel1 ? t2[2] : rr[0];  o[1] = sel1 ? t2[3] : rr[1];
    o[2] = sel1 ? rr[2] : t2[0];  o[3] = sel1 ? rr[3] : t2[1];

    // ---- gates (lane owns batch b, unit ug)
    float zi = o[0] + bf2f(pref[0]);
    float zf = o[1] + bf2f(pref[1]);
    float zg = o[2] + bf2f(pref[2]);
    float zo = o[3] + bf2f(pref[3]);
    float gi = sigm(zi), gf = sigm(zf), gg = tanh_(zg), go = sigm(zo);
    float cn = gf*c_reg + gi*gg;
    float hn = go*tanh_(cn);
    if ((mk[b][t >> 5] >> (t & 31)) & 1){ c_reg = cn; h_reg = hn; }

    // ---- publish immediately (earliest possible)
    if (s < 255){
      u32 dw = ((u32)f2bf(h_reg) << 16) | (u32)s;
      u32* gdst = img + (size_t)(s & 1)*16384 + dpub;
      asm volatile("global_store_dword %0, %1, off sc0 sc1" :: "v"(gdst), "v"(dw) : "memory");
    }
    pref = nxt;
  }

  // ---- finals
  int tl = dir ? 0 : 255;
  out[(size_t)(b*256 + tl)*1024 + dir*512 + ug] = h_reg;
  out[8388608 + dir*16384 + b*512 + ug] = h_reg;                // h_f / h_b
  out[8388608 + 32768 + dir*16384 + b*512 + ug] = c_reg;        // c_f / c_b
}

// ----------------------------------------------------------------------------
extern "C" void kernel_launch(void* const* d_in, const int* in_sizes, int n_in,
                              void* d_out, int out_size, void* d_ws, size_t ws_size,
                              hipStream_t stream){
  const int*   x   = (const int*)  d_in[0];
  const float* h0f = (const float*)d_in[1];
  const float* c0f = (const float*)d_in[2];
  const float* h0b = (const float*)d_in[3];
  const float* c0b = (const float*)d_in[4];
  const float* emb = (const float*)d_in[5];
  const float* Wf  = (const float*)d_in[6];
  const float* Uf  = (const float*)d_in[7];
  const float* bfv = (const float*)d_in[8];
  const float* Wb  = (const float*)d_in[9];
  const float* Ub  = (const float*)d_in[10];
  const float* bbv = (const float*)d_in[11];
  float* out = (float*)d_out;

  char* w = (char*)d_ws;
  u16*   aemb = (u16*)(w + OFF_AEMB);
  u16*   wpt  = (u16*)(w + OFF_WPT);
  float* bias = (float*)(w + OFF_BIAS);
  u16*   upt  = (u16*)(w + OFF_UPT);
  u32*   mskb = (u32*)(w + OFF_MASK);
  u32*   himg = (u32*)(w + OFF_HIMG);
  u16*   xw   = (u16*)(w + OFF_XW);

  k_prep  <<<dim3(8641),  dim3(320), 0, stream>>>(x, emb, Wf, Wb, bfv, bbv, Uf, Ub,
                                                  h0f, h0b, aemb, wpt, bias, upt, mskb, himg);
  k_ingemm<<<dim3(64,16), dim3(512), 0, stream>>>(aemb, wpt, bias, xw);
  k_recur <<<dim3(64),    dim3(512), 0, stream>>>(xw, upt, mskb, himg,
                                                  c0f, c0b, h0f, h0b, out);
}

// Round 11
// 853.121 us; speedup vs baseline: 1.6947x; 1.1287x over previous
//
#include <hip/hip_runtime.h>

// ============================================================================
// Bidirectional LSTM encoder, MI355X.  R11: R10 with compile fix (stray label).
//   - No xw buffer, no k_ingemm. Each k_recur wave computes its own xW tile
//     for step s+1 during the post-publish window (overlaps cross-wg sync).
//   - aemb rows double-buffered in LDS (stride 328 = bank-conflict-free);
//     stage loads issued before verify (absorbed by its vmcnt), ds_write
//     after RAWBAR (parity + barrier ordering proven).
//   - Sync machinery identical to R9: tag-in-data, 8-chunk verify/retry,
//     1 RAWBAR/step, immediate publish, in-wave quad transpose gates.
// ============================================================================

typedef unsigned short u16;
typedef unsigned int   u32;
typedef u16   u16x8 __attribute__((ext_vector_type(8)));
typedef u32   u32x4 __attribute__((ext_vector_type(4)));
typedef __bf16 bf16x8 __attribute__((ext_vector_type(8)));
typedef float f32x4 __attribute__((ext_vector_type(4)));

#define EP 320            // padded E (300 -> 320)
#define EPL 328           // LDS row stride (pad -> 2-way banks only)

static const size_t OFF_AEMB = 0;                              // 8192*320*2
static const size_t OFF_WPT  = OFF_AEMB + (size_t)8192*EP*2;
static const size_t OFF_BIAS = OFF_WPT  + (size_t)4096*EP*2;   // f32[4096]
static const size_t OFF_UPT  = OFF_BIAS + (size_t)4096*4;      // bf16 [4096][512]
static const size_t OFF_MASK = OFF_UPT  + (size_t)4096*512*2;  // u32 [32][8]
static const size_t OFF_HIMG = OFF_MASK + 1024;                // u32 2dir*2par*16384 dwords

__device__ __forceinline__ u16 f2bf(float f){               // RNE
  u32 u = __builtin_bit_cast(u32, f);
  return (u16)((u + 0x7FFFu + ((u >> 16) & 1u)) >> 16);
}
__device__ __forceinline__ float sigm(float x){ return 1.f/(1.f+__expf(-x)); }
__device__ __forceinline__ float tanh_(float x){ return 2.f/(1.f+__expf(-2.f*x)) - 1.f; }

#define RAWBAR() do{ \
  asm volatile("s_waitcnt lgkmcnt(0)" ::: "memory"); \
  __builtin_amdgcn_sched_barrier(0); \
  __builtin_amdgcn_s_barrier(); \
  __builtin_amdgcn_sched_barrier(0); \
}while(0)

// ---------------------------------------------------------------- fused prep
__global__ __launch_bounds__(320) void k_prep(const int* __restrict__ x,
                                              const float* __restrict__ emb,
                                              const float* __restrict__ Wf, const float* __restrict__ Wb,
                                              const float* __restrict__ bfv, const float* __restrict__ bbv,
                                              const float* __restrict__ Uf, const float* __restrict__ Ub,
                                              const float* __restrict__ h0f, const float* __restrict__ h0b,
                                              u16* __restrict__ aemb, u16* __restrict__ wpt,
                                              float* __restrict__ bias, u16* __restrict__ upt,
                                              u32* __restrict__ maskb, u32* __restrict__ himg){
  __shared__ u16 lbuf[320*64];                 // 40 KB, reused by wt/ut parts
  int bid = blockIdx.x, tid = threadIdx.x;

  if (bid < 8192){                             // ---- aemb gather
    int m = bid, k = tid;
    int b = m & 31, t = m >> 5;
    int tok = x[b*256 + t];
    float v = (k < 300) ? emb[(size_t)tok*300 + k] : 0.f;
    aemb[(size_t)m*EP + k] = f2bf(v);
    return;
  }
  if (bid < 8256){                             // ---- W -> [col'][K] + bias
    int b2 = bid - 8192;                       // 0..63
    u16 (*lds)[64] = (u16(*)[64])lbuf;
    int c0 = b2*64; int dir = c0 >> 11;
    const float* W = dir ? Wb : Wf;
    if (tid < 256){
      int cl = tid & 63, rr = tid >> 6;
      int ci = (c0 + cl) & 2047; int srccol = (ci & 3)*512 + (ci >> 2);
      for (int kk = 0; kk < 80; kk++){
        int row = kk*4 + rr;
        float v = (row < 300) ? W[(size_t)row*2048 + srccol] : 0.f;
        lds[row][cl] = f2bf(v);
      }
    }
    __syncthreads();
    if (tid < 256){
      int cw = tid >> 2, kc = tid & 3;
      #pragma unroll
      for (int j = 0; j < 10; j++){
        u16x8 v;
        #pragma unroll
        for (int e = 0; e < 8; e++) v[e] = lds[kc*80 + j*8 + e][cw];
        *(u16x8*)&wpt[(size_t)(c0+cw)*EP + kc*80 + j*8] = v;
      }
      if (tid < 64){
        int ci2 = (c0 + tid) & 2047; int sc = (ci2 & 3)*512 + (ci2 >> 2);
        bias[c0 + tid] = (dir ? bbv : bfv)[sc];
      }
    }
    return;
  }
  if (bid < 8384){                             // ---- U -> [col'][K]
    int b2 = bid - 8256;                       // 0..127
    u16 (*lds)[32] = (u16(*)[32])lbuf;
    int cg0 = b2*32; int dir = cg0 >> 11;
    const float* U = dir ? Ub : Uf;
    if (tid < 256){
      int cl = tid & 31, rr = tid >> 5;
      int ci = (cg0 + cl) & 2047; int srccol = (ci & 3)*512 + (ci >> 2);
      for (int kk = 0; kk < 64; kk++){
        int row = kk*8 + rr;
        lds[row][cl] = f2bf(U[(size_t)row*2048 + srccol]);
      }
    }
    __syncthreads();
    if (tid < 256){
      int cw = tid >> 3, kc = tid & 7;
      #pragma unroll
      for (int j = 0; j < 8; j++){
        u16x8 v;
        #pragma unroll
        for (int e = 0; e < 8; e++) v[e] = lds[kc*64 + j*8 + e][cw];
        *(u16x8*)&upt[(size_t)(cg0+cw)*512 + kc*64 + j*8] = v;
      }
    }
    return;
  }
  {                                            // ---- mask + tagged image init
    int b2 = bid - 8384;                       // 0..256
    if (tid >= 256) return;
    if (b2 == 256){
      int b = tid >> 3, w = tid & 7;
      u32 m = 0;
      for (int i = 0; i < 32; i++){ int t = w*32 + i; m |= (u32)(x[b*256 + t] != 0) << i; }
      maskb[b*8 + w] = m;
      return;
    }
    int idx = b2*256 + tid;                    // 0 .. 65535
    int dir = idx >> 15, rem = idx & 32767, par = rem >> 14, di = rem & 16383;
    u32* img = himg + (size_t)dir*32768 + (size_t)par*16384;
    if (par == 0){
      img[di] = 0x0000DEADu;                   // invalid tag
    } else {
      int j = di & 7, lane2 = (di >> 3) & 63, ks = (di >> 9) & 15, mt = di >> 13;
      int b = mt*16 + (lane2 & 15), ug = ks*32 + (lane2 >> 4)*8 + j;
      const float* h0 = dir ? h0b : h0f;
      img[di] = ((u32)f2bf(h0[b*512 + ug]) << 16) | 0xFFFFu;   // h_{-1}, tag -1
    }
  }
}

// ---------------------------------------------------------------- persistent recurrence + fused xW
__global__ __launch_bounds__(512) void k_recur(const u16* __restrict__ aemb, const u16* __restrict__ wpt,
                                               const float* __restrict__ bias, const u16* __restrict__ upt,
                                               const u32* __restrict__ maskb, u32* __restrict__ himg,
                                               const float* __restrict__ c0f, const float* __restrict__ c0b,
                                               const float* __restrict__ h0f, const float* __restrict__ h0b,
                                               float* __restrict__ out){
  int bid = blockIdx.x;                        // 64 wgs
  int dir = bid & 1, r = bid >> 1;             // direction, rank in group (0..31)
  int tid = threadIdx.x, lane = tid & 63, wv = tid >> 6;
  int nt = wv & 3, mt = wv >> 2;               // wave's N-tile (16 cols) and m-tile (16 rows)

  __shared__ u16 astage[2][16384];             // double-buffered h frag image (64 KB)
  __shared__ u16 aembS[2][32*EPL];             // double-buffered x-emb rows (41 KB)
  __shared__ u32 mk[32][8];

  // U-slice (full K) + W-slice (K=320) as persistent B-fragments
  bf16x8 bfr[16], wfr[10];
  {
    const u16* ub = upt + ((size_t)dir*2048 + r*64 + nt*16 + (lane & 15))*512 + ((lane >> 4)*8);
    #pragma unroll
    for (int ks = 0; ks < 16; ks++)
      bfr[ks] = __builtin_bit_cast(bf16x8, *(const u16x8*)(ub + ks*32));
    const u16* wb = wpt + ((size_t)dir*2048 + r*64 + nt*16 + (lane & 15))*EP + ((lane >> 4)*8);
    #pragma unroll
    for (int ks = 0; ks < 10; ks++)
      wfr[ks] = __builtin_bit_cast(bf16x8, *(const u16x8*)(wb + ks*32));
  }

  // lane's post-transpose gate identity (R4-validated mapping)
  int bq = (lane >> 4)*4 + (lane & 3);
  int u2 = (lane & 15) >> 2;
  int b  = mt*16 + bq;
  int ug = r*16 + nt*4 + u2;
  float c_reg = (dir ? c0b : c0f)[b*512 + ug];
  float h_reg = (dir ? h0b : h0f)[b*512 + ug];
  f32x4 biasv = *(const f32x4*)&bias[dir*2048 + ug*4];
  if (tid < 256) mk[tid >> 3][tid & 7] = maskb[tid];

  u32* img = himg + (size_t)dir*32768;
  int ksp = ug >> 5, q = (ug >> 3) & 3, jj = ug & 7;
  size_t dpub = (((size_t)mt*16 + ksp)*64 + (size_t)(q*16 + (b & 15)))*8 + jj;
  bool sel0 = (lane & 1), sel1 = (lane & 2);

  // ---------------- prologue: stage aembS[0]<-t0, aembS[1]<-t1; compute xwv(t0)
  f32x4 xwv;
  {
    int t0r = dir ? 255 : 0, t1r = dir ? 254 : 1;
    const char* s0 = (const char*)aemb + (size_t)(t0r*32)*EP*2;
    const char* s1 = (const char*)aemb + (size_t)(t1r*32)*EP*2;
    #pragma unroll
    for (int i = 0; i < 3; i++){
      int slot = tid + i*512;
      if (slot < 1280){
        u32x4 a0 = *(const u32x4*)(s0 + slot*16);
        u32x4 a1 = *(const u32x4*)(s1 + slot*16);
        int row = slot/40, k = slot - row*40;
        *(u32x4*)((char*)&aembS[0][0] + row*(EPL*2) + k*16) = a0;
        *(u32x4*)((char*)&aembS[1][0] + row*(EPL*2) + k*16) = a1;
      }
    }
    __syncthreads();
    f32x4 xacc = {0.f,0.f,0.f,0.f};
    const u16* al = &aembS[0][0] + (size_t)(mt*16 + (lane & 15))*EPL + ((lane >> 4)*8);
    #pragma unroll
    for (int ks = 0; ks < 10; ks++){
      bf16x8 a = __builtin_bit_cast(bf16x8, *(const u16x8*)(al + ks*32));
      xacc = __builtin_amdgcn_mfma_f32_16x16x32_bf16(a, wfr[ks], xacc, 0, 0, 0);
    }
    f32x4 tt, rr, t2v, o;
    #pragma unroll
    for (int e = 0; e < 4; e++) tt[e] = __shfl_xor(xacc[e], 1);
    rr[0] = sel0 ? tt[1] : xacc[0];  rr[1] = sel0 ? xacc[1] : tt[0];
    rr[2] = sel0 ? tt[3] : xacc[2];  rr[3] = sel0 ? xacc[3] : tt[2];
    #pragma unroll
    for (int e = 0; e < 4; e++) t2v[e] = __shfl_xor(rr[e], 2);
    o[0] = sel1 ? t2v[2] : rr[0];  o[1] = sel1 ? t2v[3] : rr[1];
    o[2] = sel1 ? rr[2] : t2v[0];  o[3] = sel1 ? rr[3] : t2v[1];
    #pragma unroll
    for (int e = 0; e < 4; e++) xwv[e] = o[e] + biasv[e];
  }

  for (int s = 0; s < 256; ++s){
    int t = dir ? 255 - s : s;
    u32 tg = (u32)((s - 1) & 0xFFFF);
    int pr = (s + 1) & 1;

    // ---- issue 8 tagged chunk loads (full 64KB image)
    const char* gsrc = (const char*)(img + (size_t)pr*16384) + (size_t)tid*16;
    u32x4 v0, v1, v2, v3, v4, v5, v6, v7;
    #define LD(i) asm volatile("global_load_dwordx4 %0, %1, off sc0 sc1" : "=v"(v##i) : "v"(gsrc + i*8192))
    LD(0); LD(1); LD(2); LD(3); LD(4); LD(5); LD(6); LD(7);

    // ---- issue aemb stage loads for t_{s+2} (plain cached; absorbed by verify vmcnt)
    u32x4 sg0, sg1, sg2;
    int slot0 = tid, slot1 = tid + 512, slot2 = tid + 1024;
    if (s < 254){
      int t2r = dir ? 253 - s : s + 2;
      const char* sa = (const char*)aemb + (size_t)(t2r*32)*EP*2;
      sg0 = *(const u32x4*)(sa + slot0*16);
      sg1 = *(const u32x4*)(sa + slot1*16);
      if (slot2 < 1280) sg2 = *(const u32x4*)(sa + slot2*16);
    }

    // ---- aging filler: deferred out-store of h_{s-1}
    if (s > 0){
      int tp = dir ? t + 1 : s - 1;
      out[(size_t)(b*256 + tp)*1024 + dir*512 + ug] = h_reg;
    }

    // ---- verify tags == s-1, stage verified chunks into astage[pr], retry stale
    {
      u32 pend = 255u;
      for (;;){
        asm volatile("s_waitcnt vmcnt(0)" ::: "memory");
        __builtin_amdgcn_sched_barrier(0);
        #define CK(i) if (pend & (1u << i)){ \
          if ((((v##i.x ^ tg) | (v##i.y ^ tg) | (v##i.z ^ tg) | (v##i.w ^ tg)) & 0xFFFFu) == 0u){ \
            u16 p0 = (u16)(v##i.x >> 16), p1 = (u16)(v##i.y >> 16), p2 = (u16)(v##i.z >> 16), p3 = (u16)(v##i.w >> 16); \
            u16* dst = (u16*)((char*)&astage[pr][0] + (size_t)tid*8 + i*4096); \
            dst[0] = p0; dst[1] = p1; dst[2] = p2; dst[3] = p3; \
            pend &= ~(1u << i); \
          } else { LD(i); } }
        CK(0); CK(1); CK(2); CK(3); CK(4); CK(5); CK(6); CK(7);
        #undef CK
        if (!pend) break;
      }
    }
    #undef LD
    RAWBAR();                                   // astage[pr] + prior aembS reads settled

    // ---- ds_write staged aemb rows into aembS[s&1]
    if (s < 254){
      int row0 = slot0/40, k0 = slot0 - row0*40;
      int row1 = slot1/40, k1 = slot1 - row1*40;
      *(u32x4*)((char*)&aembS[s & 1][0] + row0*(EPL*2) + k0*16) = sg0;
      *(u32x4*)((char*)&aembS[s & 1][0] + row1*(EPL*2) + k1*16) = sg1;
      if (slot2 < 1280){
        int row2 = slot2/40, k2 = slot2 - row2*40;
        *(u32x4*)((char*)&aembS[s & 1][0] + row2*(EPL*2) + k2*16) = sg2;
      }
    }

    // ---- z = h_{s-1} @ U : 16 MFMA, full K
    f32x4 acc = {0.f, 0.f, 0.f, 0.f};
    {
      const u16* ab = &astage[pr][0] + (size_t)(mt*16)*512 + lane*8;
      #pragma unroll
      for (int ks = 0; ks < 16; ks++){
        bf16x8 a = __builtin_bit_cast(bf16x8, *(const u16x8*)(ab + (size_t)ks*512));
        acc = __builtin_amdgcn_mfma_f32_16x16x32_bf16(a, bfr[ks], acc, 0, 0, 0);
      }
    }

    // ---- in-wave quad 4x4 transpose
    f32x4 tt, rr, t2v, o;
    #pragma unroll
    for (int e = 0; e < 4; e++) tt[e] = __shfl_xor(acc[e], 1);
    rr[0] = sel0 ? tt[1] : acc[0];  rr[1] = sel0 ? acc[1] : tt[0];
    rr[2] = sel0 ? tt[3] : acc[2];  rr[3] = sel0 ? acc[3] : tt[2];
    #pragma unroll
    for (int e = 0; e < 4; e++) t2v[e] = __shfl_xor(rr[e], 2);
    o[0] = sel1 ? t2v[2] : rr[0];  o[1] = sel1 ? t2v[3] : rr[1];
    o[2] = sel1 ? rr[2] : t2v[0];  o[3] = sel1 ? rr[3] : t2v[1];

    // ---- gates (lane owns batch b, unit ug); xwv = xW+b fp32 from last iter
    float zi = o[0] + xwv[0];
    float zf = o[1] + xwv[1];
    float zg = o[2] + xwv[2];
    float zo = o[3] + xwv[3];
    float gi = sigm(zi), gf = sigm(zf), gg = tanh_(zg), go = sigm(zo);
    float cn = gf*c_reg + gi*gg;
    float hn = go*tanh_(cn);
    if ((mk[b][t >> 5] >> (t & 31)) & 1){ c_reg = cn; h_reg = hn; }

    // ---- publish immediately
    if (s < 255){
      u32 dw = ((u32)f2bf(h_reg) << 16) | (u32)s;
      u32* gdst = img + (size_t)(s & 1)*16384 + dpub;
      asm volatile("global_store_dword %0, %1, off sc0 sc1" :: "v"(gdst), "v"(dw) : "memory");
    }

    // ---- compute xwv for t_{s+1} from aembS[(s+1)&1] (overlaps cross-wg sync)
    if (s < 255){
      f32x4 xacc = {0.f,0.f,0.f,0.f};
      const u16* al = &aembS[(s + 1) & 1][0] + (size_t)(mt*16 + (lane & 15))*EPL + ((lane >> 4)*8);
      #pragma unroll
      for (int ks = 0; ks < 10; ks++){
        bf16x8 a = __builtin_bit_cast(bf16x8, *(const u16x8*)(al + ks*32));
        xacc = __builtin_amdgcn_mfma_f32_16x16x32_bf16(a, wfr[ks], xacc, 0, 0, 0);
      }
      f32x4 xt, xr, x2, xo;
      #pragma unroll
      for (int e = 0; e < 4; e++) xt[e] = __shfl_xor(xacc[e], 1);
      xr[0] = sel0 ? xt[1] : xacc[0];  xr[1] = sel0 ? xacc[1] : xt[0];
      xr[2] = sel0 ? xt[3] : xacc[2];  xr[3] = sel0 ? xacc[3] : xt[2];
      #pragma unroll
      for (int e = 0; e < 4; e++) x2[e] = __shfl_xor(xr[e], 2);
      xo[0] = sel1 ? x2[2] : xr[0];  xo[1] = sel1 ? x2[3] : xr[1];
      xo[2] = sel1 ? xr[2] : x2[0];  xo[3] = sel1 ? xr[3] : x2[1];
      #pragma unroll
      for (int e = 0; e < 4; e++) xwv[e] = xo[e] + biasv[e];
    }
  }

  // ---- finals
  int tl = dir ? 0 : 255;
  out[(size_t)(b*256 + tl)*1024 + dir*512 + ug] = h_reg;
  out[8388608 + dir*16384 + b*512 + ug] = h_reg;                // h_f / h_b
  out[8388608 + 32768 + dir*16384 + b*512 + ug] = c_reg;        // c_f / c_b
}

// ----------------------------------------------------------------------------
extern "C" void kernel_launch(void* const* d_in, const int* in_sizes, int n_in,
                              void* d_out, int out_size, void* d_ws, size_t ws_size,
                              hipStream_t stream){
  const int*   x   = (const int*)  d_in[0];
  const float* h0f = (const float*)d_in[1];
  const float* c0f = (const float*)d_in[2];
  const float* h0b = (const float*)d_in[3];
  const float* c0b = (const float*)d_in[4];
  const float* emb = (const float*)d_in[5];
  const float* Wf  = (const float*)d_in[6];
  const float* Uf  = (const float*)d_in[7];
  const float* bfv = (const float*)d_in[8];
  const float* Wb  = (const float*)d_in[9];
  const float* Ub  = (const float*)d_in[10];
  const float* bbv = (const float*)d_in[11];
  float* out = (float*)d_out;

  char* w = (char*)d_ws;
  u16*   aemb = (u16*)(w + OFF_AEMB);
  u16*   wpt  = (u16*)(w + OFF_WPT);
  float* bias = (float*)(w + OFF_BIAS);
  u16*   upt  = (u16*)(w + OFF_UPT);
  u32*   mskb = (u32*)(w + OFF_MASK);
  u32*   himg = (u32*)(w + OFF_HIMG);

  k_prep <<<dim3(8641), dim3(320), 0, stream>>>(x, emb, Wf, Wb, bfv, bbv, Uf, Ub,
                                                h0f, h0b, aemb, wpt, bias, upt, mskb, himg);
  k_recur<<<dim3(64),   dim3(512), 0, stream>>>(aemb, wpt, bias, upt, mskb, himg,
                                                c0f, c0b, h0f, h0b, out);
}

// Round 12
// 656.665 us; speedup vs baseline: 2.2018x; 1.2992x over previous
//
#include <hip/hip_runtime.h>

// ============================================================================
// Bidirectional LSTM encoder, MI355X.  R12: 4 sync domains (dir x batch-half).
//   - batch rows 0-15 / 16-31 are independent recurrences -> 4 domains x 16
//     wgs. Per wg: 16 rows x 128 cols; 8 waves x (16x16 tile, 16 MFMA full-K).
//   - h image per domain: 16x512 bf16 = 8192 tagged dwords (32KB). Verify = 4
//     chunks/thread. Publish = quad-packed global_store_dwordx4 (128/wg).
//   - xW fold, tag-in-data, 1 RAWBAR/step, in-wave quad transpose: as R11.
// ============================================================================

typedef unsigned short u16;
typedef unsigned int   u32;
typedef u16   u16x8 __attribute__((ext_vector_type(8)));
typedef u32   u32x4 __attribute__((ext_vector_type(4)));
typedef __bf16 bf16x8 __attribute__((ext_vector_type(8)));
typedef float f32x4 __attribute__((ext_vector_type(4)));

#define EP 320            // padded E (300 -> 320)
#define EPL 328           // LDS row stride (pad -> 2-way banks only)

static const size_t OFF_AEMB = 0;                              // 8192*320*2
static const size_t OFF_WPT  = OFF_AEMB + (size_t)8192*EP*2;
static const size_t OFF_BIAS = OFF_WPT  + (size_t)4096*EP*2;   // f32[4096]
static const size_t OFF_UPT  = OFF_BIAS + (size_t)4096*4;      // bf16 [4096][512]
static const size_t OFF_MASK = OFF_UPT  + (size_t)4096*512*2;  // u32 [32][8]
static const size_t OFF_HIMG = OFF_MASK + 1024;                // u32 4dom*2par*8192 dwords

__device__ __forceinline__ u16 f2bf(float f){               // RNE
  u32 u = __builtin_bit_cast(u32, f);
  return (u16)((u + 0x7FFFu + ((u >> 16) & 1u)) >> 16);
}
__device__ __forceinline__ float sigm(float x){ return 1.f/(1.f+__expf(-x)); }
__device__ __forceinline__ float tanh_(float x){ return 2.f/(1.f+__expf(-2.f*x)) - 1.f; }

#define RAWBAR() do{ \
  asm volatile("s_waitcnt lgkmcnt(0)" ::: "memory"); \
  __builtin_amdgcn_sched_barrier(0); \
  __builtin_amdgcn_s_barrier(); \
  __builtin_amdgcn_sched_barrier(0); \
}while(0)

// ---------------------------------------------------------------- fused prep
__global__ __launch_bounds__(320) void k_prep(const int* __restrict__ x,
                                              const float* __restrict__ emb,
                                              const float* __restrict__ Wf, const float* __restrict__ Wb,
                                              const float* __restrict__ bfv, const float* __restrict__ bbv,
                                              const float* __restrict__ Uf, const float* __restrict__ Ub,
                                              const float* __restrict__ h0f, const float* __restrict__ h0b,
                                              u16* __restrict__ aemb, u16* __restrict__ wpt,
                                              float* __restrict__ bias, u16* __restrict__ upt,
                                              u32* __restrict__ maskb, u32* __restrict__ himg){
  __shared__ u16 lbuf[320*64];                 // 40 KB, reused by wt/ut parts
  int bid = blockIdx.x, tid = threadIdx.x;

  if (bid < 8192){                             // ---- aemb gather
    int m = bid, k = tid;
    int b = m & 31, t = m >> 5;
    int tok = x[b*256 + t];
    float v = (k < 300) ? emb[(size_t)tok*300 + k] : 0.f;
    aemb[(size_t)m*EP + k] = f2bf(v);
    return;
  }
  if (bid < 8256){                             // ---- W -> [col'][K] + bias
    int b2 = bid - 8192;                       // 0..63
    u16 (*lds)[64] = (u16(*)[64])lbuf;
    int c0 = b2*64; int dir = c0 >> 11;
    const float* W = dir ? Wb : Wf;
    if (tid < 256){
      int cl = tid & 63, rr = tid >> 6;
      int ci = (c0 + cl) & 2047; int srccol = (ci & 3)*512 + (ci >> 2);
      for (int kk = 0; kk < 80; kk++){
        int row = kk*4 + rr;
        float v = (row < 300) ? W[(size_t)row*2048 + srccol] : 0.f;
        lds[row][cl] = f2bf(v);
      }
    }
    __syncthreads();
    if (tid < 256){
      int cw = tid >> 2, kc = tid & 3;
      #pragma unroll
      for (int j = 0; j < 10; j++){
        u16x8 v;
        #pragma unroll
        for (int e = 0; e < 8; e++) v[e] = lds[kc*80 + j*8 + e][cw];
        *(u16x8*)&wpt[(size_t)(c0+cw)*EP + kc*80 + j*8] = v;
      }
      if (tid < 64){
        int ci2 = (c0 + tid) & 2047; int sc = (ci2 & 3)*512 + (ci2 >> 2);
        bias[c0 + tid] = (dir ? bbv : bfv)[sc];
      }
    }
    return;
  }
  if (bid < 8384){                             // ---- U -> [col'][K]
    int b2 = bid - 8256;                       // 0..127
    u16 (*lds)[32] = (u16(*)[32])lbuf;
    int cg0 = b2*32; int dir = cg0 >> 11;
    const float* U = dir ? Ub : Uf;
    if (tid < 256){
      int cl = tid & 31, rr = tid >> 5;
      int ci = (cg0 + cl) & 2047; int srccol = (ci & 3)*512 + (ci >> 2);
      for (int kk = 0; kk < 64; kk++){
        int row = kk*8 + rr;
        lds[row][cl] = f2bf(U[(size_t)row*2048 + srccol]);
      }
    }
    __syncthreads();
    if (tid < 256){
      int cw = tid >> 3, kc = tid & 7;
      #pragma unroll
      for (int j = 0; j < 8; j++){
        u16x8 v;
        #pragma unroll
        for (int e = 0; e < 8; e++) v[e] = lds[kc*64 + j*8 + e][cw];
        *(u16x8*)&upt[(size_t)(cg0+cw)*512 + kc*64 + j*8] = v;
      }
    }
    return;
  }
  {                                            // ---- mask + tagged image init
    int b2 = bid - 8384;                       // 0..256
    if (tid >= 256) return;
    if (b2 == 256){
      int b = tid >> 3, w = tid & 7;
      u32 m = 0;
      for (int i = 0; i < 32; i++){ int t = w*32 + i; m |= (u32)(x[b*256 + t] != 0) << i; }
      maskb[b*8 + w] = m;
      return;
    }
    int idx = b2*256 + tid;                    // 0 .. 65535
    int dom = idx >> 14, rem = idx & 16383, par = rem >> 13, di = rem & 8191;
    int dir = dom >> 1, bh = dom & 1;
    u32* img = himg + (size_t)dom*16384 + (size_t)par*8192;
    if (par == 0){
      img[di] = 0x0000DEADu;                   // invalid tag
    } else {
      int j = di & 7, lane2 = (di >> 3) & 63, ks = di >> 9;
      int bl = lane2 & 15, q = lane2 >> 4;
      int ug = ks*32 + q*8 + j;
      int b = bh*16 + bl;
      const float* h0 = dir ? h0b : h0f;
      img[di] = ((u32)f2bf(h0[b*512 + ug]) << 16) | 0xFFFFu;   // h_{-1}, tag -1
    }
  }
}

// ---------------------------------------------------------------- persistent recurrence + fused xW
__global__ __launch_bounds__(512) void k_recur(const u16* __restrict__ aemb, const u16* __restrict__ wpt,
                                               const float* __restrict__ bias, const u16* __restrict__ upt,
                                               const u32* __restrict__ maskb, u32* __restrict__ himg,
                                               const float* __restrict__ c0f, const float* __restrict__ c0b,
                                               const float* __restrict__ h0f, const float* __restrict__ h0b,
                                               float* __restrict__ out){
  int bid = blockIdx.x;                        // 64 wgs
  int dir = bid & 1, bh = (bid >> 1) & 1, r = bid >> 2;   // domain (dir,bh), rank 0..15
  int tid = threadIdx.x, lane = tid & 63, wv = tid >> 6;
  int nt = wv;                                 // wave's N-tile (16 of the wg's 128 cols)

  __shared__ u16 astage[2][8192];              // double-buffered h frag image (32 KB)
  __shared__ u16 aembS[2][16*EPL];             // double-buffered x-emb rows (20.5 KB)
  __shared__ u32 mk[32][8];

  // U-slice (full K) + W-slice (K=320) as persistent B-fragments
  bf16x8 bfr[16], wfr[10];
  {
    const u16* ub = upt + ((size_t)dir*2048 + r*128 + nt*16 + (lane & 15))*512 + ((lane >> 4)*8);
    #pragma unroll
    for (int ks = 0; ks < 16; ks++)
      bfr[ks] = __builtin_bit_cast(bf16x8, *(const u16x8*)(ub + ks*32));
    const u16* wb = wpt + ((size_t)dir*2048 + r*128 + nt*16 + (lane & 15))*EP + ((lane >> 4)*8);
    #pragma unroll
    for (int ks = 0; ks < 10; ks++)
      wfr[ks] = __builtin_bit_cast(bf16x8, *(const u16x8*)(wb + ks*32));
  }

  // lane's post-transpose gate identity (R4-validated mapping)
  int bq = (lane >> 4)*4 + (lane & 3);         // local batch row 0..15
  int u2 = (lane & 15) >> 2;
  int b  = bh*16 + bq;                         // global batch row
  int ug = r*32 + nt*4 + u2;
  float c_reg = (dir ? c0b : c0f)[b*512 + ug];
  float h_reg = (dir ? h0b : h0f)[b*512 + ug];
  f32x4 biasv = *(const f32x4*)&bias[dir*2048 + ug*4];
  if (tid < 256) mk[tid >> 3][tid & 7] = maskb[tid];

  u32* img = himg + (size_t)(dir*2 + bh)*16384;
  int qq = nt >> 1, j0 = (nt*4) & 7;
  size_t dpub = ((size_t)(r*64 + qq*16 + bq))*8 + j0;   // dword idx within parity buf
  bool sel0 = (lane & 1), sel1 = (lane & 2);
  int lb48 = lane & 48;

  // ---------------- prologue: stage aembS[0]<-t0, aembS[1]<-t1; compute xwv(t0)
  f32x4 xwv;
  {
    int t0r = dir ? 255 : 0, t1r = dir ? 254 : 1;
    const char* s0 = (const char*)aemb + ((size_t)(t0r*32 + bh*16))*EP*2;
    const char* s1 = (const char*)aemb + ((size_t)(t1r*32 + bh*16))*EP*2;
    {
      u32x4 a0 = *(const u32x4*)(s0 + (size_t)tid*16);
      u32x4 a1 = *(const u32x4*)(s1 + (size_t)tid*16);
      int row = tid/40, k = tid - (tid/40)*40;
      *(u32x4*)((char*)&aembS[0][0] + row*(EPL*2) + k*16) = a0;
      *(u32x4*)((char*)&aembS[1][0] + row*(EPL*2) + k*16) = a1;
      if (tid < 128){
        int sl = 512 + tid;
        u32x4 b0 = *(const u32x4*)(s0 + (size_t)sl*16);
        u32x4 b1 = *(const u32x4*)(s1 + (size_t)sl*16);
        int row2 = sl/40, k2 = sl - (sl/40)*40;
        *(u32x4*)((char*)&aembS[0][0] + row2*(EPL*2) + k2*16) = b0;
        *(u32x4*)((char*)&aembS[1][0] + row2*(EPL*2) + k2*16) = b1;
      }
    }
    __syncthreads();
    f32x4 xacc = {0.f,0.f,0.f,0.f};
    const u16* al = &aembS[0][0] + (size_t)(lane & 15)*EPL + ((lane >> 4)*8);
    #pragma unroll
    for (int ks = 0; ks < 10; ks++){
      bf16x8 a = __builtin_bit_cast(bf16x8, *(const u16x8*)(al + ks*32));
      xacc = __builtin_amdgcn_mfma_f32_16x16x32_bf16(a, wfr[ks], xacc, 0, 0, 0);
    }
    f32x4 tt, rr, t2v, o;
    #pragma unroll
    for (int e = 0; e < 4; e++) tt[e] = __shfl_xor(xacc[e], 1);
    rr[0] = sel0 ? tt[1] : xacc[0];  rr[1] = sel0 ? xacc[1] : tt[0];
    rr[2] = sel0 ? tt[3] : xacc[2];  rr[3] = sel0 ? xacc[3] : tt[2];
    #pragma unroll
    for (int e = 0; e < 4; e++) t2v[e] = __shfl_xor(rr[e], 2);
    o[0] = sel1 ? t2v[2] : rr[0];  o[1] = sel1 ? t2v[3] : rr[1];
    o[2] = sel1 ? rr[2] : t2v[0];  o[3] = sel1 ? rr[3] : t2v[1];
    #pragma unroll
    for (int e = 0; e < 4; e++) xwv[e] = o[e] + biasv[e];
  }

  for (int s = 0; s < 256; ++s){
    int t = dir ? 255 - s : s;
    u32 tg = (u32)((s - 1) & 0xFFFF);
    int pr = (s + 1) & 1;

    // ---- issue 4 tagged chunk loads (full 32KB domain image)
    const char* gsrc = (const char*)(img + (size_t)pr*8192) + (size_t)tid*16;
    u32x4 v0, v1, v2, v3;
    #define LD(i) asm volatile("global_load_dwordx4 %0, %1, off sc0 sc1" : "=v"(v##i) : "v"(gsrc + i*8192))
    LD(0); LD(1); LD(2); LD(3);

    // ---- issue aemb stage loads for t_{s+2} (cached; absorbed by verify vmcnt)
    u32x4 sg0, sg1;
    if (s < 254){
      int t2r = dir ? 253 - s : s + 2;
      const char* sa = (const char*)aemb + ((size_t)(t2r*32 + bh*16))*EP*2;
      sg0 = *(const u32x4*)(sa + (size_t)tid*16);
      if (tid < 128) sg1 = *(const u32x4*)(sa + (size_t)(512 + tid)*16);
    }

    // ---- aging filler: deferred out-store of h_{s-1}
    if (s > 0){
      int tp = dir ? t + 1 : s - 1;
      out[(size_t)(b*256 + tp)*1024 + dir*512 + ug] = h_reg;
    }

    // ---- verify tags == s-1, stage verified chunks into astage[pr], retry stale
    {
      u32 pend = 15u;
      for (;;){
        asm volatile("s_waitcnt vmcnt(0)" ::: "memory");
        __builtin_amdgcn_sched_barrier(0);
        #define CK(i) if (pend & (1u << i)){ \
          if ((((v##i.x ^ tg) | (v##i.y ^ tg) | (v##i.z ^ tg) | (v##i.w ^ tg)) & 0xFFFFu) == 0u){ \
            u16 p0 = (u16)(v##i.x >> 16), p1 = (u16)(v##i.y >> 16), p2 = (u16)(v##i.z >> 16), p3 = (u16)(v##i.w >> 16); \
            u16* dst = (u16*)((char*)&astage[pr][0] + (size_t)tid*8 + i*4096); \
            dst[0] = p0; dst[1] = p1; dst[2] = p2; dst[3] = p3; \
            pend &= ~(1u << i); \
          } else { LD(i); } }
        CK(0); CK(1); CK(2); CK(3);
        #undef CK
        if (!pend) break;
      }
    }
    #undef LD
    RAWBAR();                                   // astage[pr] ready (single barrier/step)

    // ---- ds_write staged aemb rows into aembS[s&1]
    if (s < 254){
      int row0 = tid/40, k0 = tid - (tid/40)*40;
      *(u32x4*)((char*)&aembS[s & 1][0] + row0*(EPL*2) + k0*16) = sg0;
      if (tid < 128){
        int sl = 512 + tid;
        int row1 = sl/40, k1 = sl - (sl/40)*40;
        *(u32x4*)((char*)&aembS[s & 1][0] + row1*(EPL*2) + k1*16) = sg1;
      }
    }

    // ---- z = h_{s-1} @ U : 16 MFMA, full K
    f32x4 acc = {0.f, 0.f, 0.f, 0.f};
    {
      const u16* ab = &astage[pr][0] + lane*8;
      #pragma unroll
      for (int ks = 0; ks < 16; ks++){
        bf16x8 a = __builtin_bit_cast(bf16x8, *(const u16x8*)(ab + (size_t)ks*512));
        acc = __builtin_amdgcn_mfma_f32_16x16x32_bf16(a, bfr[ks], acc, 0, 0, 0);
      }
    }

    // ---- in-wave quad 4x4 transpose
    f32x4 tt, rr, t2v, o;
    #pragma unroll
    for (int e = 0; e < 4; e++) tt[e] = __shfl_xor(acc[e], 1);
    rr[0] = sel0 ? tt[1] : acc[0];  rr[1] = sel0 ? acc[1] : tt[0];
    rr[2] = sel0 ? tt[3] : acc[2];  rr[3] = sel0 ? acc[3] : tt[2];
    #pragma unroll
    for (int e = 0; e < 4; e++) t2v[e] = __shfl_xor(rr[e], 2);
    o[0] = sel1 ? t2v[2] : rr[0];  o[1] = sel1 ? t2v[3] : rr[1];
    o[2] = sel1 ? rr[2] : t2v[0];  o[3] = sel1 ? rr[3] : t2v[1];

    // ---- gates (lane owns batch b, unit ug); xwv = xW+b fp32 from last iter
    float zi = o[0] + xwv[0];
    float zf = o[1] + xwv[1];
    float zg = o[2] + xwv[2];
    float zo = o[3] + xwv[3];
    float gi = sigm(zi), gf = sigm(zf), gg = tanh_(zg), go = sigm(zo);
    float cn = gf*c_reg + gi*gg;
    float hn = go*tanh_(cn);
    if ((mk[b][t >> 5] >> (t & 31)) & 1){ c_reg = cn; h_reg = hn; }

    // ---- publish: quad-packed tagged dwordx4 (one store per 4 lanes)
    {
      float hA = __shfl(h_reg, lb48 | ((lane + 4)  & 15));
      float hB = __shfl(h_reg, lb48 | ((lane + 8)  & 15));
      float hC = __shfl(h_reg, lb48 | ((lane + 12) & 15));
      if (u2 == 0 && s < 255){
        u32 tgp = (u32)s;
        u32x4 dw;
        dw.x = ((u32)f2bf(h_reg) << 16) | tgp;
        dw.y = ((u32)f2bf(hA)    << 16) | tgp;
        dw.z = ((u32)f2bf(hB)    << 16) | tgp;
        dw.w = ((u32)f2bf(hC)    << 16) | tgp;
        u32* gdst = img + (size_t)(s & 1)*8192 + dpub;
        asm volatile("global_store_dwordx4 %0, %1, off sc0 sc1" :: "v"(gdst), "v"(dw) : "memory");
      }
    }

    // ---- compute xwv for t_{s+1} from aembS[(s+1)&1] (overlaps cross-wg sync)
    if (s < 255){
      f32x4 xacc = {0.f,0.f,0.f,0.f};
      const u16* al = &aembS[(s + 1) & 1][0] + (size_t)(lane & 15)*EPL + ((lane >> 4)*8);
      #pragma unroll
      for (int ks = 0; ks < 10; ks++){
        bf16x8 a = __builtin_bit_cast(bf16x8, *(const u16x8*)(al + ks*32));
        xacc = __builtin_amdgcn_mfma_f32_16x16x32_bf16(a, wfr[ks], xacc, 0, 0, 0);
      }
      f32x4 xt, xr, x2, xo;
      #pragma unroll
      for (int e = 0; e < 4; e++) xt[e] = __shfl_xor(xacc[e], 1);
      xr[0] = sel0 ? xt[1] : xacc[0];  xr[1] = sel0 ? xacc[1] : xt[0];
      xr[2] = sel0 ? xt[3] : xacc[2];  xr[3] = sel0 ? xacc[3] : xt[2];
      #pragma unroll
      for (int e = 0; e < 4; e++) x2[e] = __shfl_xor(xr[e], 2);
      xo[0] = sel1 ? x2[2] : xr[0];  xo[1] = sel1 ? x2[3] : xr[1];
      xo[2] = sel1 ? xr[2] : x2[0];  xo[3] = sel1 ? xr[3] : x2[1];
      #pragma unroll
      for (int e = 0; e < 4; e++) xwv[e] = xo[e] + biasv[e];
    }
  }

  // ---- finals
  int tl = dir ? 0 : 255;
  out[(size_t)(b*256 + tl)*1024 + dir*512 + ug] = h_reg;
  out[8388608 + dir*16384 + b*512 + ug] = h_reg;                // h_f / h_b
  out[8388608 + 32768 + dir*16384 + b*512 + ug] = c_reg;        // c_f / c_b
}

// ----------------------------------------------------------------------------
extern "C" void kernel_launch(void* const* d_in, const int* in_sizes, int n_in,
                              void* d_out, int out_size, void* d_ws, size_t ws_size,
                              hipStream_t stream){
  const int*   x   = (const int*)  d_in[0];
  const float* h0f = (const float*)d_in[1];
  const float* c0f = (const float*)d_in[2];
  const float* h0b = (const float*)d_in[3];
  const float* c0b = (const float*)d_in[4];
  const float* emb = (const float*)d_in[5];
  const float* Wf  = (const float*)d_in[6];
  const float* Uf  = (const float*)d_in[7];
  const float* bfv = (const float*)d_in[8];
  const float* Wb  = (const float*)d_in[9];
  const float* Ub  = (const float*)d_in[10];
  const float* bbv = (const float*)d_in[11];
  float* out = (float*)d_out;

  char* w = (char*)d_ws;
  u16*   aemb = (u16*)(w + OFF_AEMB);
  u16*   wpt  = (u16*)(w + OFF_WPT);
  float* bias = (float*)(w + OFF_BIAS);
  u16*   upt  = (u16*)(w + OFF_UPT);
  u32*   mskb = (u32*)(w + OFF_MASK);
  u32*   himg = (u32*)(w + OFF_HIMG);

  k_prep <<<dim3(8641), dim3(320), 0, stream>>>(x, emb, Wf, Wb, bfv, bbv, Uf, Ub,
                                                h0f, h0b, aemb, wpt, bias, upt, mskb, himg);
  k_recur<<<dim3(64),   dim3(512), 0, stream>>>(aemb, wpt, bias, upt, mskb, himg,
                                                c0f, c0b, h0f, h0b, out);
}